// Round 1
// baseline (201.665 us; speedup 1.0000x reference)
//
#include <hip/hip_runtime.h>
#include <stdint.h>
#include <stddef.h>

// MatchLSTMAttention: B=64, T=2048, inp_p=inp_q=out=512
// out[b] = concat(input_p[b], z[b]); z = softmax_t(w . tanh(prq[b] + iq[b,t] @ Wq^T) + match_b) @ iq[b]

#define B_ 64
#define T_ 2048
#define D_ 512

typedef __attribute__((ext_vector_type(8))) short short8;
typedef __attribute__((ext_vector_type(4))) unsigned short ushort4v;
typedef __attribute__((ext_vector_type(8))) unsigned short ushort8v;
typedef __attribute__((ext_vector_type(4))) float f32x4;

__device__ __forceinline__ unsigned short f2bf(float f) {
    unsigned int u = __builtin_bit_cast(unsigned int, f);
    return (unsigned short)((u + 0x7FFFu + ((u >> 16) & 1u)) >> 16);  // RNE
}

// ---------- kernel 0: Wq fp32 -> bf16 ----------
__global__ __launch_bounds__(256) void k_convert(const float* __restrict__ Wq,
                                                 unsigned short* __restrict__ Wq_bf) {
    int i = (blockIdx.x * 256 + threadIdx.x) * 8;
    float4 a = *(const float4*)(Wq + i);
    float4 b = *(const float4*)(Wq + i + 4);
    ushort8v o;
    o[0] = f2bf(a.x); o[1] = f2bf(a.y); o[2] = f2bf(a.z); o[3] = f2bf(a.w);
    o[4] = f2bf(b.x); o[5] = f2bf(b.y); o[6] = f2bf(b.z); o[7] = f2bf(b.w);
    *(ushort8v*)(Wq_bf + i) = o;
}

// ---------- kernel 1: prq[b,o] = ip.Wp^T + h.Wr^T + bp + bq + br ----------
__global__ __launch_bounds__(256) void k_prq(
        const float* __restrict__ ip, const float* __restrict__ h,
        const float* __restrict__ Wp, const float* __restrict__ Wr,
        const float* __restrict__ bp, const float* __restrict__ bq,
        const float* __restrict__ br, float* __restrict__ prq) {
    __shared__ float ip_lds[64][68];   // pad 68: distinct banks (4*b+k), 16B-aligned rows
    __shared__ float h_lds[64][68];
    __shared__ float wp_lds[8][68];
    __shared__ float wr_lds[8][68];
    const int tid = threadIdx.x;
    const int o0 = blockIdx.x * 8;      // 64 blocks x 8 o's
    const int bb = tid >> 3;            // 0..31
    const int oo = tid & 7;
    float acc0 = 0.f, acc1 = 0.f;
    const int lrow = tid >> 2;          // 0..63
    const int lcol = (tid & 3) * 16;    // 0,16,32,48
    for (int kc = 0; kc < 512; kc += 64) {
        #pragma unroll
        for (int j = 0; j < 16; j += 4) {
            float4 v = *(const float4*)(ip + lrow * 512 + kc + lcol + j);
            ip_lds[lrow][lcol + j] = v.x; ip_lds[lrow][lcol + j + 1] = v.y;
            ip_lds[lrow][lcol + j + 2] = v.z; ip_lds[lrow][lcol + j + 3] = v.w;
            float4 u = *(const float4*)(h + lrow * 512 + kc + lcol + j);
            h_lds[lrow][lcol + j] = u.x; h_lds[lrow][lcol + j + 1] = u.y;
            h_lds[lrow][lcol + j + 2] = u.z; h_lds[lrow][lcol + j + 3] = u.w;
        }
        if (tid < 128) {
            int r = tid >> 4, c = (tid & 15) * 4;
            float4 v = *(const float4*)(Wp + (size_t)(o0 + r) * 512 + kc + c);
            wp_lds[r][c] = v.x; wp_lds[r][c + 1] = v.y; wp_lds[r][c + 2] = v.z; wp_lds[r][c + 3] = v.w;
        } else {
            int t2 = tid - 128;
            int r = t2 >> 4, c = (t2 & 15) * 4;
            float4 v = *(const float4*)(Wr + (size_t)(o0 + r) * 512 + kc + c);
            wr_lds[r][c] = v.x; wr_lds[r][c + 1] = v.y; wr_lds[r][c + 2] = v.z; wr_lds[r][c + 3] = v.w;
        }
        __syncthreads();
        #pragma unroll 4
        for (int k = 0; k < 64; ++k) {
            float wpv = wp_lds[oo][k], wrv = wr_lds[oo][k];
            acc0 += ip_lds[bb][k] * wpv + h_lds[bb][k] * wrv;
            acc1 += ip_lds[bb + 32][k] * wpv + h_lds[bb + 32][k] * wrv;
        }
        __syncthreads();
    }
    const int o = o0 + oo;
    float base = bp[o] + bq[o] + br[o];
    prq[bb * 512 + o] = acc0 + base;
    prq[(bb + 32) * 512 + o] = acc1 + base;
}

// ---------- kernel 2: fused Gq GEMM + tanh + w-reduction -> logits[b,t] ----------
// BM=64 (rows of flattened [B*T]), BN=512 (full), BK=32, 8 waves (2m x 4n), per-wave 32x128.
__global__ __launch_bounds__(512, 1) void k_gq(
        const float* __restrict__ iq, const unsigned short* __restrict__ Wq_bf,
        const float* __restrict__ prq, const float* __restrict__ wv,
        const float* __restrict__ match_b, float* __restrict__ logits) {
    __shared__ unsigned short A_t[64][32];   // 16B-chunk XOR swizzle: chunk ^= (row>>1)&3
    __shared__ unsigned short B_t[512][32];
    __shared__ float w_lds[512];
    __shared__ float prq_lds[512];
    __shared__ float red[4][64];

    const int tid = threadIdx.x;
    const int m0 = blockIdx.x * 64;          // 2048 blocks; each block within one b (2048%64==0)
    const int b = m0 >> 11;
    w_lds[tid] = wv[tid];
    prq_lds[tid] = prq[b * 512 + tid];

    const int lane = tid & 63;
    const int wave = tid >> 6;
    const int wm = wave >> 2;                // 0..1
    const int wn = wave & 3;                 // 0..3
    const int r16 = lane & 15;
    const int cc = lane >> 4;                // k-chunk 0..3 (8 bf16 each)

    f32x4 acc[2][8];
    #pragma unroll
    for (int i = 0; i < 2; ++i)
        #pragma unroll
        for (int j = 0; j < 8; ++j) acc[i][j] = (f32x4){0.f, 0.f, 0.f, 0.f};

    // A staging: 64 rows x 32 k = 512 tasks of 4 floats
    const int arow = tid >> 3;
    const int koff = (tid & 7) * 4;
    const int adst = (((koff >> 3) ^ ((arow >> 1) & 3)) << 3) + (koff & 7);
    const float* aptr = iq + (size_t)(m0 + arow) * 512 + koff;

    const int aro0 = wm * 32 + r16;
    const int aro1 = aro0 + 16;
    const int aofs0 = ((cc ^ ((aro0 >> 1) & 3)) << 3);
    const int aofs1 = ((cc ^ ((aro1 >> 1) & 3)) << 3);

    for (int k0 = 0; k0 < 512; k0 += 32) {
        // stage A (fp32 -> bf16)
        float4 av = *(const float4*)(aptr + k0);
        ushort4v ap;
        ap[0] = f2bf(av.x); ap[1] = f2bf(av.y); ap[2] = f2bf(av.z); ap[3] = f2bf(av.w);
        *(ushort4v*)&A_t[arow][adst] = ap;
        // stage B: 512 rows x 4 16B-chunks; consecutive lanes -> consecutive chunks (coalesced)
        #pragma unroll
        for (int i = 0; i < 4; ++i) {
            int task = i * 512 + tid;
            int brow = task >> 2;
            int bch = task & 3;
            short8 v = *(const short8*)(Wq_bf + (size_t)brow * 512 + k0 + bch * 8);
            *(short8*)&B_t[brow][((bch ^ ((brow >> 1) & 3)) << 3)] = v;
        }
        __syncthreads();
        // compute
        short8 a0 = *(const short8*)&A_t[aro0][aofs0];
        short8 a1 = *(const short8*)&A_t[aro1][aofs1];
        #pragma unroll
        for (int nf = 0; nf < 8; ++nf) {
            int brow = wn * 128 + nf * 16 + r16;
            short8 bfr = *(const short8*)&B_t[brow][((cc ^ ((brow >> 1) & 3)) << 3)];
            acc[0][nf] = __builtin_amdgcn_mfma_f32_16x16x32_bf16(a0, bfr, acc[0][nf], 0, 0, 0);
            acc[1][nf] = __builtin_amdgcn_mfma_f32_16x16x32_bf16(a1, bfr, acc[1][nf], 0, 0, 0);
        }
        __syncthreads();
    }

    // epilogue: logit contribution = sum_o w[o] * tanh(acc + prq[o])
    float part[2][4];
    #pragma unroll
    for (int mf = 0; mf < 2; ++mf)
        #pragma unroll
        for (int j = 0; j < 4; ++j) part[mf][j] = 0.f;

    #pragma unroll
    for (int nf = 0; nf < 8; ++nf) {
        int c = wn * 128 + nf * 16 + r16;
        float wc = w_lds[c];
        float pc = prq_lds[c];
        #pragma unroll
        for (int mf = 0; mf < 2; ++mf) {
            #pragma unroll
            for (int j = 0; j < 4; ++j) {
                float x = acc[mf][nf][j] + pc;
                float e = __expf(2.f * x);               // fast tanh: 1 - 2/(e^2x + 1)
                float g = 1.f - 2.f / (e + 1.f);
                part[mf][j] += wc * g;
            }
        }
    }
    // reduce across the 16 col-lanes of each 16-lane group
    #pragma unroll
    for (int mf = 0; mf < 2; ++mf)
        #pragma unroll
        for (int j = 0; j < 4; ++j) {
            float v = part[mf][j];
            v += __shfl_xor(v, 1);
            v += __shfl_xor(v, 2);
            v += __shfl_xor(v, 4);
            v += __shfl_xor(v, 8);
            part[mf][j] = v;
        }
    if (r16 == 0) {
        int rg = (lane >> 4) * 4;
        #pragma unroll
        for (int mf = 0; mf < 2; ++mf)
            #pragma unroll
            for (int j = 0; j < 4; ++j)
                red[wn][wm * 32 + mf * 16 + rg + j] = part[mf][j];
    }
    __syncthreads();
    if (tid < 64) {
        float l = red[0][tid] + red[1][tid] + red[2][tid] + red[3][tid] + match_b[0];
        logits[m0 + tid] = l;
    }
}

// ---------- kernel 3: softmax stats per b; copy input_p -> out; zero z ----------
__global__ __launch_bounds__(256) void k_stats(const float* __restrict__ logits,
                                               const float* __restrict__ ip,
                                               float* __restrict__ out,
                                               float* __restrict__ stats) {
    const int b = blockIdx.x, tid = threadIdx.x;
    __shared__ float sm[256];
    float m = -1e30f;
    for (int i = tid; i < 2048; i += 256) m = fmaxf(m, logits[b * 2048 + i]);
    sm[tid] = m;
    __syncthreads();
    for (int s = 128; s > 0; s >>= 1) {
        if (tid < s) sm[tid] = fmaxf(sm[tid], sm[tid + s]);
        __syncthreads();
    }
    float bmax = sm[0];
    __syncthreads();
    float ssum = 0.f;
    for (int i = tid; i < 2048; i += 256) ssum += __expf(logits[b * 2048 + i] - bmax);
    sm[tid] = ssum;
    __syncthreads();
    for (int s = 128; s > 0; s >>= 1) {
        if (tid < s) sm[tid] += sm[tid + s];
        __syncthreads();
    }
    if (tid == 0) { stats[b * 2] = bmax; stats[b * 2 + 1] = sm[0]; }
    out[b * 1024 + tid] = ip[b * 512 + tid];
    out[b * 1024 + 256 + tid] = ip[b * 512 + 256 + tid];
    out[b * 1024 + 512 + tid] = 0.f;
    out[b * 1024 + 768 + tid] = 0.f;
}

// ---------- kernel 4: z[b,q] += sum_t alpha[b,t] * iq[b,t,q] ----------
#define NC 16
#define TC 128
__global__ __launch_bounds__(256) void k_z(const float* __restrict__ logits,
                                           const float* __restrict__ stats,
                                           const float* __restrict__ iq,
                                           float* __restrict__ out) {
    const int blk = blockIdx.x;
    const int b = blk >> 4;
    const int c = blk & 15;
    const int tid = threadIdx.x;
    __shared__ float al[TC];
    const float bmax = stats[b * 2];
    const float inv = 1.f / stats[b * 2 + 1];
    if (tid < TC) al[tid] = __expf(logits[b * 2048 + c * TC + tid] - bmax) * inv;
    __syncthreads();
    const int q = tid * 2;
    float ax = 0.f, ay = 0.f;
    const float* base = iq + ((size_t)b * 2048 + (size_t)c * TC) * 512 + q;
    #pragma unroll 4
    for (int t = 0; t < TC; ++t) {
        float2 v = *(const float2*)(base + (size_t)t * 512);
        float a = al[t];
        ax += a * v.x;
        ay += a * v.y;
    }
    atomicAdd(&out[b * 1024 + 512 + q], ax);
    atomicAdd(&out[b * 1024 + 512 + q + 1], ay);
}

extern "C" void kernel_launch(void* const* d_in, const int* in_sizes, int n_in,
                              void* d_out, int out_size, void* d_ws, size_t ws_size,
                              hipStream_t stream) {
    const float* input_p = (const float*)d_in[0];
    const float* input_q = (const float*)d_in[1];
    const float* h_tm1   = (const float*)d_in[2];
    const float* Wp      = (const float*)d_in[3];
    const float* bp      = (const float*)d_in[4];
    const float* Wq      = (const float*)d_in[5];
    const float* bq      = (const float*)d_in[6];
    const float* Wr      = (const float*)d_in[7];
    const float* br      = (const float*)d_in[8];
    const float* wv      = (const float*)d_in[9];
    const float* match_b = (const float*)d_in[10];
    float* out = (float*)d_out;

    char* ws = (char*)d_ws;
    unsigned short* Wq_bf = (unsigned short*)ws;            // 512 KB
    float* prq    = (float*)(ws + 512 * 1024);              // 128 KB
    float* logits = (float*)(ws + 640 * 1024);              // 512 KB
    float* stats  = (float*)(ws + 1152 * 1024);             // 512 B
    // total ws use: ~1.2 MB

    k_convert<<<dim3(128), dim3(256), 0, stream>>>(Wq, Wq_bf);
    k_prq<<<dim3(64), dim3(256), 0, stream>>>(input_p, h_tm1, Wp, Wr, bp, bq, br, prq);
    k_gq<<<dim3(2048), dim3(512), 0, stream>>>(input_q, Wq_bf, prq, wv, match_b, logits);
    k_stats<<<dim3(64), dim3(256), 0, stream>>>(logits, input_p, out, stats);
    k_z<<<dim3(64 * 16), dim3(256), 0, stream>>>(logits, stats, input_q, out);
}